// Round 20
// baseline (1506.436 us; speedup 1.0000x reference)
//
#include <hip/hip_runtime.h>
#include <hip/hip_bf16.h>

#define SEQ   20
#define PRED  30
#define TSTEPS (SEQ + PRED)
#define PEDS  16384
#define RNN   128
#define PB    64
#define NT    512
#define L2E   1.44269504f
#define ABUF  24576

typedef _Float16 half8 __attribute__((ext_vector_type(8)));
typedef __attribute__((ext_vector_type(4))) float f32x4;
typedef __attribute__((ext_vector_type(2))) float f32x2;

// Raw barrier: publish LDS writes, leave vmem (B-prefetch) in flight.
#define RAW_BAR() do {                                          \
    asm volatile("s_waitcnt lgkmcnt(0)" ::: "memory");          \
    __builtin_amdgcn_s_barrier();                               \
    asm volatile("" ::: "memory");                              \
    __builtin_amdgcn_sched_barrier(0);                          \
} while (0)

__device__ __forceinline__ float sigm2(float xp) {
    return __builtin_amdgcn_rcpf(1.f + __builtin_amdgcn_exp2f(-xp));
}
__device__ __forceinline__ float tanh2p(float xp) {
    float r = __builtin_amdgcn_rcpf(__builtin_amdgcn_exp2f(xp + xp) + 1.f);
    return fmaf(-2.f, r, 1.f);
}
__device__ __forceinline__ float tanh2u(float x) {
    float r = __builtin_amdgcn_rcpf(__builtin_amdgcn_exp2f(x * (2.f * L2E)) + 1.f);
    return fmaf(-2.f, r, 1.f);
}

// Bp (f16, PRESCALED by log2e): idx = ((kt*32 + nt)*64 + l)*8 + i
// nt = g*8 + jt ; row n = g*128 + jt*16 + (l&15) ; k = kt*32 + (l>>4)*8 + i
// ewp[ke][4] = {Wemb[ke][0], Wemb[ke][1], bemb[ke], 0}
__global__ void prep_kernel(const float* __restrict__ Wih, const float* __restrict__ Whh,
                            const float* __restrict__ Wemb, const float* __restrict__ bemb,
                            _Float16* __restrict__ Bp, float* __restrict__ ewp) {
    int t = blockIdx.x * blockDim.x + threadIdx.x;
    if (t < 64) {
        ewp[t * 4 + 0] = Wemb[t * 2 + 0];
        ewp[t * 4 + 1] = Wemb[t * 2 + 1];
        ewp[t * 4 + 2] = bemb[t];
        ewp[t * 4 + 3] = 0.f;
    }
    if (t >= 6 * 32 * 64 * 8) return;
    int i  = t & 7;
    int l  = (t >> 3) & 63;
    int nt = (t >> 9) & 31;
    int kt = t >> 14;
    int n = (nt >> 3) * RNN + (nt & 7) * 16 + (l & 15);
    int k = kt * 32 + ((l >> 4) << 3) + i;
    float val = (k < 64) ? Wih[n * 64 + k] : Whh[n * RNN + (k - 64)];
    Bp[t] = (_Float16)(val * L2E);
}

// Two phase-shifted ped-groups (waves 0-3: peds 0-31; waves 4-7: peds 32-63).
// Each half-phase one group runs G (MFMA) while the other runs S/O (VALU);
// the workgroup barrier is the shared clock. Peds are fully independent, so
// the groups share no data; smB duplicate staging writes identical bytes.
__global__ __launch_bounds__(NT, 2) void lstm_kernel(
    const float* __restrict__ obs,
    const float* __restrict__ ewp,
    const float* __restrict__ bih,  const float* __restrict__ bhh,
    const _Float16* __restrict__ Bp,
    const float* __restrict__ Wout, const float* __restrict__ bout,
    float* __restrict__ out)
{
    __shared__ __align__(16) char smA[2 * ABUF];     // 48 KB A dbuf (e+h f16)
    __shared__ __align__(16) char smB[2 * 32768];    // 64 KB B dbuf
    __shared__ float smObs[SEQ * 128];               // 10 KB
    __shared__ float smEW[64 * 4];
    __shared__ float smWO[256];

    const int tid = threadIdx.x;
    const int l   = tid & 63;
    const int w   = __builtin_amdgcn_readfirstlane(tid >> 6);  // wave 0..7
    const int gp  = w >> 2;         // group 0/1
    const int v   = w & 3;          // wave-in-group (j-tile pair {v, v+4})
    const int gped = gp * 32;

    for (int r = tid; r < (2 * ABUF) / 4; r += NT) ((int*)smA)[r] = 0;
    if (tid < 64) *(f32x4*)(smEW + tid * 4) = *(const f32x4*)(ewp + tid * 4);
    if (tid < 256) smWO[tid] = Wout[tid];
    for (int i = tid; i < SEQ * 128; i += NT) {
        int st = i >> 7, r = i & 127;
        smObs[i] = obs[(size_t)st * (PEDS * 2) + blockIdx.x * 128 + r];
    }
    const float bout0 = bout[0], bout1 = bout[1];

    const int lrow = (l >> 4) << 2;
    const int swz  = (l & 7) << 4;
    const int jl[2] = { v * 16 + (l & 15), (v + 4) * 16 + (l & 15) };

    float bias[2][4];
#pragma unroll
    for (int h = 0; h < 2; ++h)
#pragma unroll
        for (int g = 0; g < 4; ++g) {
            int n = g * RNN + jl[h];
            bias[h][g] = (bih[n] + bhh[n]) * L2E;
        }

    // ---- addresses (step-invariant) ----
    int aBase[2];
#pragma unroll
    for (int m = 0; m < 2; ++m)
        aBase[m] = (gped + m * 16 + (l & 15)) * 384 + ((l >> 4) << 4);
    int sAddr[2][4];
#pragma unroll
    for (int h = 0; h < 2; ++h)
#pragma unroll
        for (int r = 0; r < 4; ++r)
            sAddr[h][r] = ((gped + lrow + r) * 384 + 128 + jl[h] * 2) ^ (((lrow + r) & 7) << 4);
    // O/E mapping: wave owns 8 peds; 8 lanes per ped
    const int orow = gped + v * 8 + (l >> 3);
    const int oswz = ((l >> 3) & 7) << 4;
    int oAddr[2];
#pragma unroll
    for (int t2 = 0; t2 < 2; ++t2)
        oAddr[t2] = (orow * 384 + 128 + (l & 7) * 32 + t2 * 16) ^ oswz;
    const int eAddr8 = (orow * 384 + (l & 7) * 16) ^ oswz;
    // encode-E mapping: 32 peds x 2 col-halves per group
    const int cped  = gped + (l & 31);
    const int cAddr = (cped * 384 + v * 32 + (l >> 5) * 16) ^ ((l & 7) << 4);

    const char* bb = smB + l * 16;
    const char* srcB = (const char*)Bp + l * 16;

    auto stage = [&](int slice, int buf) {
#pragma unroll
        for (int g4 = 0; g4 < 4; ++g4)
#pragma unroll
            for (int hh = 0; hh < 2; ++hh) {
                int nt = g4 * 8 + v + hh * 4;
                __builtin_amdgcn_global_load_lds(
                    (const __attribute__((address_space(1))) void*)(srcB + slice * 32768 + nt * 1024),
                    (__attribute__((address_space(3))) void*)(smB + buf * 32768 + nt * 1024 + l * 16),
                    16, 0, 0);
            }
    };

    float c[16];
#pragma unroll
    for (int q = 0; q < 16; ++q) c[q] = 0.f;
    f32x4 acc[2][2][4];  // [jt-half][mt][gate], live G->S across one barrier

    stage(0, 0);
    __syncthreads();
    {   // E(0) for own group's peds (O-phase shape, x from smObs[0])
        float x0 = smObs[orow * 2 + 0], x1 = smObs[orow * 2 + 1];
        half8 vh;
#pragma unroll
        for (int i = 0; i < 8; ++i) {
            const f32x4 ew = *(const f32x4*)(smEW + ((l & 7) * 8 + i) * 4);
            float val = fmaf(x0, ew[0], fmaf(x1, ew[1], ew[2]));
            vh[i] = (_Float16)fmaxf(val, 0.f);
        }
        *(half8*)(smA + 0 + eAddr8) = vh;
    }
    __syncthreads();

    const int NQ = 2 * SEQ + 3 * PRED + 1;  // 131 phases per group
    for (int hp = 0; hp < NQ + 1; ++hp) {
        const int q = hp - gp;
        if (q >= 0 && q < NQ) {
            int t, sub;
            if (q < 2 * SEQ) { t = q >> 1; sub = (q & 1) ? 2 : 1; }   // G / S(+E)
            else { int r = q - 2 * SEQ; t = SEQ + r / 3; sub = r % 3; } // O,G,S

            if (sub == 0) {
                // ---- O(t-1): out(t-1) + e(t); h(t-1) is in buffer cur(t)
                const int hb = (t & 1) * ABUF;
                float s0 = 0.f, s1 = 0.f;
#pragma unroll
                for (int t2 = 0; t2 < 2; ++t2) {
                    half8 hh8 = *(const half8*)(smA + hb + oAddr[t2]);
#pragma unroll
                    for (int i = 0; i < 8; ++i) {
                        float hv = (float)hh8[i];
                        int j = (l & 7) * 16 + t2 * 8 + i;
                        s0 = fmaf(hv, smWO[j], s0);
                        s1 = fmaf(hv, smWO[128 + j], s1);
                    }
                }
                s0 += __shfl_xor(s0, 1); s1 += __shfl_xor(s1, 1);
                s0 += __shfl_xor(s0, 2); s1 += __shfl_xor(s1, 2);
                s0 += __shfl_xor(s0, 4); s1 += __shfl_xor(s1, 4);
                s0 += bout0; s1 += bout1;
                if ((l & 7) == 0 && t - 1 >= SEQ) {
                    f32x2 ov; ov[0] = s0; ov[1] = s1;
                    *(f32x2*)(out + ((size_t)(t - 1 - SEQ) * PEDS + blockIdx.x * PB + orow) * 2) = ov;
                }
                if (t < TSTEPS) {
                    half8 vh;
#pragma unroll
                    for (int i = 0; i < 8; ++i) {
                        const f32x4 ew = *(const f32x4*)(smEW + ((l & 7) * 8 + i) * 4);
                        float val = fmaf(s0, ew[0], fmaf(s1, ew[1], ew[2]));
                        vh[i] = (_Float16)fmaxf(val, 0.f);
                    }
                    *(half8*)(smA + hb + eAddr8) = vh;
                }
            } else if (sub == 1) {
                // ---- G(t): gates = A @ B + bias'
                const int cur = (t & 1) * ABUF;
#pragma unroll
                for (int h = 0; h < 2; ++h)
#pragma unroll
                    for (int m = 0; m < 2; ++m)
#pragma unroll
                        for (int g = 0; g < 4; ++g) {
                            acc[h][m][g][0] = bias[h][g]; acc[h][m][g][1] = bias[h][g];
                            acc[h][m][g][2] = bias[h][g]; acc[h][m][g][3] = bias[h][g];
                        }
#pragma unroll
                for (int kt = 0; kt < 6; ++kt) {
                    const int buf = kt & 1;
                    stage((kt < 5) ? kt + 1 : 0, buf ^ 1);
                    asm volatile("s_waitcnt vmcnt(8)" ::: "memory");
                    half8 ah[2];
#pragma unroll
                    for (int m = 0; m < 2; ++m)
                        ah[m] = *(const half8*)(smA + cur + ((aBase[m] + kt * 64) ^ swz));
#pragma unroll
                    for (int hh = 0; hh < 2; ++hh) {
                        half8 bf[4];
#pragma unroll
                        for (int g = 0; g < 4; ++g)
                            bf[g] = *(const half8*)(bb + buf * 32768 + ((g * 8 + v + hh * 4) * 1024));
                        __builtin_amdgcn_s_setprio(1);
#pragma unroll
                        for (int m = 0; m < 2; ++m)
#pragma unroll
                            for (int g = 0; g < 4; ++g)
                                acc[hh][m][g] = __builtin_amdgcn_mfma_f32_16x16x32_f16(ah[m], bf[g], acc[hh][m][g], 0, 0, 0);
                        __builtin_amdgcn_s_setprio(0);
                    }
                }
            } else {
                // ---- S(t): nonlinearities + c/h update; h -> cur(t)^ABUF
                const int nxt = ((t & 1) * ABUF) ^ ABUF;
#pragma unroll
                for (int h = 0; h < 2; ++h)
#pragma unroll
                    for (int m = 0; m < 2; ++m)
#pragma unroll
                        for (int r = 0; r < 4; ++r) {
                            float gi = acc[h][m][0][r], gf = acc[h][m][1][r];
                            float gg = acc[h][m][2][r], go = acc[h][m][3][r];
                            float i_ = sigm2(gi), f_ = sigm2(gf), g_ = tanh2p(gg), o_ = sigm2(go);
                            int ci = h * 8 + m * 4 + r;
                            float cn = fmaf(f_, c[ci], i_ * g_);
                            c[ci] = cn;
                            float hn = o_ * tanh2u(cn);
                            *(_Float16*)(smA + nxt + sAddr[h][r] + m * 6144) = (_Float16)hn;
                        }
                // encode: also compute e(t+1) from obs into the same nxt buffer
                if (t < SEQ - 1) {
                    float x0 = smObs[(t + 1) * 128 + cped * 2 + 0];
                    float x1 = smObs[(t + 1) * 128 + cped * 2 + 1];
                    half8 vh;
#pragma unroll
                    for (int q2 = 0; q2 < 8; ++q2) {
                        int k = v * 16 + (l >> 5) * 8 + q2;
                        const f32x4 ew = *(const f32x4*)(smEW + k * 4);
                        float val = fmaf(x0, ew[0], fmaf(x1, ew[1], ew[2]));
                        vh[q2] = (_Float16)fmaxf(val, 0.f);
                    }
                    *(half8*)(smA + nxt + cAddr) = vh;
                }
            }
        }
        RAW_BAR();
    }
}

extern "C" void kernel_launch(void* const* d_in, const int* in_sizes, int n_in,
                              void* d_out, int out_size, void* d_ws, size_t ws_size,
                              hipStream_t stream) {
    const float* obs  = (const float*)d_in[0];
    const float* Wemb = (const float*)d_in[1];
    const float* bemb = (const float*)d_in[2];
    const float* Wih  = (const float*)d_in[3];
    const float* bih  = (const float*)d_in[4];
    const float* Whh  = (const float*)d_in[5];
    const float* bhh  = (const float*)d_in[6];
    const float* Wout = (const float*)d_in[7];
    const float* bout = (const float*)d_in[8];

    _Float16* Bp  = (_Float16*)d_ws;                 // 98304 f16 = 192 KB
    float*    ewp = (float*)(Bp + 6 * 32 * 64 * 8);  // 64*4 f32 = 1 KB

    prep_kernel<<<(6 * 32 * 64 * 8 + 255) / 256, 256, 0, stream>>>(Wih, Whh, Wemb, bemb, Bp, ewp);
    lstm_kernel<<<PEDS / PB, NT, 0, stream>>>(obs, ewp, bih, bhh, Bp, Wout, bout, (float*)d_out);
}

// Round 21
// 227.809 us; speedup vs baseline: 6.6127x; 6.6127x over previous
//
#include <hip/hip_runtime.h>
#include <hip/hip_bf16.h>

#define SEQ   20
#define PRED  30
#define TSTEPS (SEQ + PRED)
#define PEDS  16384
#define EMB   64
#define RNN   128
#define PB    64
#define NT    512
#define L2E   1.44269504f

typedef _Float16 half8 __attribute__((ext_vector_type(8)));
typedef __attribute__((ext_vector_type(4))) float f32x4;
typedef __attribute__((ext_vector_type(2))) float f32x2;

// Raw barrier: publish LDS writes (lgkmcnt) but leave vmem (B-prefetch) in flight.
#define RAW_BAR() do {                                          \
    asm volatile("s_waitcnt lgkmcnt(0)" ::: "memory");          \
    __builtin_amdgcn_s_barrier();                               \
    asm volatile("" ::: "memory");                              \
    __builtin_amdgcn_sched_barrier(0);                          \
} while (0)

__device__ __forceinline__ float sigm2(float xp) {
    return __builtin_amdgcn_rcpf(1.f + __builtin_amdgcn_exp2f(-xp));
}
__device__ __forceinline__ float tanh2p(float xp) {
    float r = __builtin_amdgcn_rcpf(__builtin_amdgcn_exp2f(xp + xp) + 1.f);
    return fmaf(-2.f, r, 1.f);
}
__device__ __forceinline__ float tanh2u(float x) {
    float r = __builtin_amdgcn_rcpf(__builtin_amdgcn_exp2f(x * (2.f * L2E)) + 1.f);
    return fmaf(-2.f, r, 1.f);
}

// B fragments (f16, PRESCALED by log2e): idx = ((kt*32 + nt)*64 + l)*8 + i
// nt = g*8 + jt ; row n = g*128 + jt*16 + (l&15) ; k = kt*32 + (l>>4)*8 + i
// ewp[ke][4] = {Wemb[ke][0], Wemb[ke][1], bemb[ke], 0}  (unscaled)
__global__ void prep_kernel(const float* __restrict__ Wih, const float* __restrict__ Whh,
                            const float* __restrict__ Wemb, const float* __restrict__ bemb,
                            _Float16* __restrict__ Bp, float* __restrict__ ewp) {
    int t = blockIdx.x * blockDim.x + threadIdx.x;
    if (t < 64) {
        ewp[t * 4 + 0] = Wemb[t * 2 + 0];
        ewp[t * 4 + 1] = Wemb[t * 2 + 1];
        ewp[t * 4 + 2] = bemb[t];
        ewp[t * 4 + 3] = 0.f;
    }
    if (t >= 6 * 32 * 64 * 8) return;
    int i  = t & 7;
    int l  = (t >> 3) & 63;
    int nt = (t >> 9) & 31;
    int kt = t >> 14;
    int n = (nt >> 3) * RNN + (nt & 7) * 16 + (l & 15);
    int k = kt * 32 + ((l >> 4) << 3) + i;
    float val = (k < EMB) ? Wih[n * EMB + k] : Whh[n * RNN + (k - EMB)];
    Bp[t] = (_Float16)(val * L2E);
}

__global__ __launch_bounds__(NT, 2) void lstm_kernel(
    const float* __restrict__ obs,
    const float* __restrict__ ewp,
    const float* __restrict__ bih,  const float* __restrict__ bhh,
    const _Float16* __restrict__ Bp,
    const float* __restrict__ Wout, const float* __restrict__ bout,
    float* __restrict__ out)
{
    __shared__ __align__(16) char smA[2 * 24576];    // 48 KB A dbuf (e+h f16)
    __shared__ __align__(16) char smB[3 * 32768];    // 96 KB B triple-buf
    __shared__ float smObs[SEQ * 128];               // 10 KB this block's obs
    __shared__ float smEW[64 * 4];                   // embedding weights
    __shared__ float smWO[256];                      // Wout [o][j]
    __shared__ float part[64 * 2 * 4];               // 2 KB
    __shared__ float outs[64 * 2];

    const int tid = threadIdx.x;
    const int l   = tid & 63;
    const int w   = __builtin_amdgcn_readfirstlane(tid >> 6);  // wave 0..7 (= jt)

    for (int r = tid; r < (2 * 24576) / 4; r += NT) ((int*)smA)[r] = 0;
    if (tid < 64) *(f32x4*)(smEW + tid * 4) = *(const f32x4*)(ewp + tid * 4);
    if (tid < 256) smWO[tid] = Wout[tid];
    // obs slab: smObs[step*128 + r] = obs[step*PEDS*2 + blockIdx*128 + r]
    for (int i = tid; i < SEQ * 128; i += NT) {
        int st = i >> 7, r = i & 127;
        smObs[i] = obs[(size_t)st * (PEDS * 2) + blockIdx.x * 128 + r];
    }

    const int jlane = w * 16 + (l & 15);
    const int lrow  = (l >> 4) << 2;
    const int swz   = (l & 7) << 4;

    float bias[4];
#pragma unroll
    for (int g = 0; g < 4; ++g) {
        int n = g * RNN + jlane;
        bias[g] = (bih[n] + bhh[n]) * L2E;
    }

    // ---- step-invariant addresses ----
    int aBase[4];
#pragma unroll
    for (int mt = 0; mt < 4; ++mt) {
        int ped = mt * 16 + (l & 15);
        aBase[mt] = ped * 384 + ((l >> 4) << 4);
    }
    int sAddr[4];
#pragma unroll
    for (int r = 0; r < 4; ++r) {
        int ped = lrow + r;
        sAddr[r] = (ped * 384 + 128 + jlane * 2) ^ ((ped & 7) << 4);
    }
    const int eAddr = (l * 384 + w * 16) ^ swz;
    const int oBase = l * 384 + 128 + (w >> 1) * 64;
    const char* bb  = smB + l * 16;
    const char* stageSrc = (const char*)Bp + l * 16 + w * 1024;
    const float* woBase = smWO + (w & 1) * 128 + (w >> 1) * 32;

    // stage slice (0..5) into buf slice%3: wave stages exactly the 4 frags it reads
    auto stage = [&](int slice) {
        const int buf = slice % 3;
#pragma unroll
        for (int g = 0; g < 4; ++g) {
            const void* src = stageSrc + slice * 32768 + g * 8192;
            __builtin_amdgcn_global_load_lds(
                (const __attribute__((address_space(1))) void*)src,
                (__attribute__((address_space(3))) void*)(smB + buf * 32768 + (g * 8 + w) * 1024),
                16, 0, 0);
        }
    };

    float c[16];
#pragma unroll
    for (int q = 0; q < 16; ++q) c[q] = 0.f;

    stage(0);
    stage(1);
    __syncthreads();  // one-time full drain: slices 0,1 + obs/EW/WO/A-zero published

    int curOff = 0;

    for (int step = 0; step < TSTEPS; ++step) {
        const int nxtOff = curOff ^ 24576;

        // ---- E: e = relu(x @ Wemb.T + bemb) -> A[cur] k=0..63 (all from LDS)
        {
            float x0, x1;
            if (step < SEQ) {
                f32x2 xv = *(const f32x2*)(smObs + step * 128 + l * 2);
                x0 = xv[0]; x1 = xv[1];
            } else {
                x0 = outs[l * 2 + 0];
                x1 = outs[l * 2 + 1];
            }
            half8 vh;
#pragma unroll
            for (int q = 0; q < 8; ++q) {
                const f32x4 ew = *(const f32x4*)(smEW + (w * 8 + q) * 4);
                float v = fmaf(x0, ew[0], fmaf(x1, ew[1], ew[2]));
                vh[q] = (_Float16)fmaxf(v, 0.f);
            }
            *(half8*)(smA + curOff + eAddr) = vh;
        }
        RAW_BAR();  // B1: e(step) + h(step-1) visible; B-prefetch stays in flight

        // ---- G: gates = A @ B + bias' ; f16 1-pass; depth-2 staged pipeline
        f32x4 acc[4][4];
#pragma unroll
        for (int mt = 0; mt < 4; ++mt)
#pragma unroll
            for (int g = 0; g < 4; ++g) {
                acc[mt][g][0] = bias[g]; acc[mt][g][1] = bias[g];
                acc[mt][g][2] = bias[g]; acc[mt][g][3] = bias[g];
            }
#pragma unroll
        for (int kt = 0; kt < 6; ++kt) {
            const int buf = kt % 3;
            stage((kt < 4) ? kt + 2 : kt - 4);  // depth-2; kt>=4 stages next step's slices
            // slice kt's 4 loads are 8 deep (kt-1's 4 + kt's 4 are newer)
            asm volatile("s_waitcnt vmcnt(8)" ::: "memory");
            half8 bf[4];
#pragma unroll
            for (int g = 0; g < 4; ++g)
                bf[g] = *(const half8*)(bb + buf * 32768 + (g * 8 + w) * 1024);
#pragma unroll
            for (int mt = 0; mt < 4; ++mt) {
                half8 ah = *(const half8*)(smA + curOff + ((aBase[mt] + kt * 64) ^ swz));
#pragma unroll
                for (int g = 0; g < 4; ++g)
                    acc[mt][g] = __builtin_amdgcn_mfma_f32_16x16x32_f16(ah, bf[g], acc[mt][g], 0, 0, 0);
            }
        }
        // no barrier: S writes A[nxt], lagging G reads A[cur]

        // ---- S: nonlinearities (prescaled) + c/h update; h -> A[nxt]
#pragma unroll
        for (int mt = 0; mt < 4; ++mt) {
#pragma unroll
            for (int r = 0; r < 4; ++r) {
                float gi = acc[mt][0][r], gf = acc[mt][1][r];
                float gg = acc[mt][2][r], go = acc[mt][3][r];
                float i_ = sigm2(gi), f_ = sigm2(gf), g_ = tanh2p(gg), o_ = sigm2(go);
                float cn = fmaf(f_, c[mt * 4 + r], i_ * g_);
                c[mt * 4 + r] = cn;
                float hn = o_ * tanh2u(cn);
                *(_Float16*)(smA + nxtOff + sAddr[r] + mt * 6144) = (_Float16)hn;
            }
        }

        // ---- O: out = h @ Wout.T + bout (part[]-reduced, Wout from LDS)
        if (step >= SEQ - 1) {
            RAW_BAR();  // h(step) visible
            {
                const int oo = w & 1;
                float s = 0.f;
#pragma unroll
                for (int t = 0; t < 4; ++t) {
                    half8 hh8 = *(const half8*)(smA + nxtOff + ((oBase + t * 16) ^ swz));
                    const f32x4 w0 = *(const f32x4*)(woBase + t * 8);
                    const f32x4 w1 = *(const f32x4*)(woBase + t * 8 + 4);
#pragma unroll
                    for (int i = 0; i < 4; ++i) {
                        s = fmaf((float)hh8[i], w0[i], s);
                        s = fmaf((float)hh8[i + 4], w1[i], s);
                    }
                }
                part[(l * 2 + oo) * 4 + (w >> 1)] = s;
            }
            RAW_BAR();
            if (tid < 128) {
                int pp = tid & 63, o2 = tid >> 6;
                const float* pr = &part[(pp * 2 + o2) * 4];
                float o = bout[o2] + ((pr[0] + pr[1]) + (pr[2] + pr[3]));
                outs[pp * 2 + o2] = o;
                if (step >= SEQ)
                    out[((size_t)(step - SEQ) * PEDS + blockIdx.x * PB + pp) * 2 + o2] = o;
            }
            RAW_BAR();  // outs visible for next E
        }
        curOff = nxtOff;
    }
}

extern "C" void kernel_launch(void* const* d_in, const int* in_sizes, int n_in,
                              void* d_out, int out_size, void* d_ws, size_t ws_size,
                              hipStream_t stream) {
    const float* obs  = (const float*)d_in[0];
    const float* Wemb = (const float*)d_in[1];
    const float* bemb = (const float*)d_in[2];
    const float* Wih  = (const float*)d_in[3];
    const float* bih  = (const float*)d_in[4];
    const float* Whh  = (const float*)d_in[5];
    const float* bhh  = (const float*)d_in[6];
    const float* Wout = (const float*)d_in[7];
    const float* bout = (const float*)d_in[8];

    _Float16* Bp  = (_Float16*)d_ws;                 // 98304 f16 = 192 KB
    float*    ewp = (float*)(Bp + 6 * 32 * 64 * 8);  // 64*4 f32 = 1 KB

    prep_kernel<<<(6 * 32 * 64 * 8 + 255) / 256, 256, 0, stream>>>(Wih, Whh, Wemb, bemb, Bp, ewp);
    lstm_kernel<<<PEDS / PB, NT, 0, stream>>>(obs, ewp, bih, bhh, Bp, Wout, bout, (float*)d_out);
}